// Round 9
// baseline (2379.563 us; speedup 1.0000x reference)
//
#include <hip/hip_runtime.h>
#include <hip/hip_bf16.h>
#include <cstdint>
#include <cstddef>

// BiLSTM tagger, f32 end-to-end.
// embed -> [GEMM pre -> 40-block LSTM scan] x2 -> MLP GEMMs (dual) -> bilinear.
// Scan design (r9): EMBRACE weight streaming from L2, scaled to 40 CUs.
// r3-r8 lesson: the allocator never keeps a >64-VGPR loop-invariant weight array
// live (remat or spill, budgets 64-132 regardless of attributes). So: 20 parts/dir,
// 40 rows/block -> 32 KB/block/step L2 stream (~500 cy at ~64 B/cy/CU), issued
// EARLY each iteration (before the exchange spin) so stream latency and partner
// latency overlap. Chunk order rotates with t ((i+t)%25) so the addresses are NOT
// loop-invariant -> no hoist/remat games; sched_barrier(0) pins issue placement.
// Per-thread transient = 25 float2 = 50 VGPRs (fits any observed budget with
// __launch_bounds__(192,2)). Cross-block h exchange: packed (tag<<32|value) u64
// words in L2, double-buffered by parity; reader spins on the data word itself.

#define TSEQ 512
#define HDIR 200
#define INSZ 400
#define G4   800
#define NPART 20
#define HPB  10     // h-indices per block (HDIR/NPART)
#define ROWS 40     // gate rows per block (4*HPB)

typedef unsigned long long u64;

// ---------------- embedding ----------------
__global__ void k_embed(const float* __restrict__ we, const float* __restrict__ pe,
                        const int* __restrict__ wi, const int* __restrict__ pi,
                        float* __restrict__ x) {
  int t = blockIdx.x;
  int w = wi[t], p = pi[t];
  const float* wrow = we + (size_t)w * 300;
  const float* prow = pe + (size_t)p * 100;
  for (int j = threadIdx.x; j < INSZ; j += blockDim.x)
    x[(size_t)t * INSZ + j] = (j < 300) ? wrow[j] : prow[j - 300];
}

__global__ void k_add(const float* __restrict__ a, const float* __restrict__ b,
                      float* __restrict__ o, int n) {
  int i = blockIdx.x * blockDim.x + threadIdx.x;
  if (i < n) o[i] = a[i] + b[i];
}

// ---------------- GEMM: C[n][m] = act(A[n][k] * B[m][k]^T + bias) ----------------
__device__ __forceinline__ void gemm_bt_body(
    const float* __restrict__ A, const float* __restrict__ B,
    const float* __restrict__ bias, float* __restrict__ C,
    int m, int k, int bias_mode, int do_relu, int bx, int by)
{
  __shared__ float As[16][68];
  __shared__ float Bs[16][68];
  const int tid = threadIdx.x;
  const int tx = tid & 15, ty = tid >> 4;
  const int row0 = by << 6, col0 = bx << 6;
  const int lr = tid >> 2;
  const int kq = (tid & 3) << 2;
  float acc[4][4] = {};

  for (int ks = 0; ks < k; ks += 16) {
    float4 a4 = *(const float4*)(A + (size_t)(row0 + lr) * k + ks + kq);
    float4 b4 = make_float4(0.f, 0.f, 0.f, 0.f);
    if (col0 + lr < m)
      b4 = *(const float4*)(B + (size_t)(col0 + lr) * k + ks + kq);
    As[kq + 0][lr] = a4.x; As[kq + 1][lr] = a4.y; As[kq + 2][lr] = a4.z; As[kq + 3][lr] = a4.w;
    Bs[kq + 0][lr] = b4.x; Bs[kq + 1][lr] = b4.y; Bs[kq + 2][lr] = b4.z; Bs[kq + 3][lr] = b4.w;
    __syncthreads();
#pragma unroll
    for (int kk = 0; kk < 16; ++kk) {
      const float4 av = *(const float4*)&As[kk][ty << 2];
      const float4 bv = *(const float4*)&Bs[kk][tx << 2];
      const float a_[4] = {av.x, av.y, av.z, av.w};
      const float b_[4] = {bv.x, bv.y, bv.z, bv.w};
#pragma unroll
      for (int i = 0; i < 4; ++i)
#pragma unroll
        for (int j = 0; j < 4; ++j)
          acc[i][j] += a_[i] * b_[j];
    }
    __syncthreads();
  }

#pragma unroll
  for (int i = 0; i < 4; ++i) {
    const int r = row0 + (ty << 2) + i;
#pragma unroll
    for (int j = 0; j < 4; ++j) {
      const int c = col0 + (tx << 2) + j;
      if (c < m) {
        float v = acc[i][j];
        if (bias_mode == 1) v += bias[c];
        else if (bias_mode == 2) v += bias[0];
        if (do_relu) v = fmaxf(v, 0.f);
        C[(size_t)r * m + c] = v;
      }
    }
  }
}

__global__ __launch_bounds__(256) void k_gemm_bt(
    const float* __restrict__ A, const float* __restrict__ B,
    const float* __restrict__ bias, float* __restrict__ C,
    int m, int k, int bias_mode, int do_relu)
{
  gemm_bt_body(A, B, bias, C, m, k, bias_mode, do_relu, blockIdx.x, blockIdx.y);
}

__global__ __launch_bounds__(256) void k_gemm_bt_dual(
    const float* __restrict__ A0, const float* __restrict__ B0,
    const float* __restrict__ bias0, float* __restrict__ C0,
    const float* __restrict__ A1, const float* __restrict__ B1,
    const float* __restrict__ bias1, float* __restrict__ C1,
    int m, int k, int bias_mode, int do_relu)
{
  const float* A = blockIdx.z ? A1 : A0;
  const float* B = blockIdx.z ? B1 : B0;
  const float* bias = blockIdx.z ? bias1 : bias0;
  float* C = blockIdx.z ? C1 : C0;
  gemm_bt_body(A, B, bias, C, m, k, bias_mode, do_relu, blockIdx.x, blockIdx.y);
}

// ---------------- LSTM scan ----------------
// grid = 40 blocks x 192 threads. dir = bid&1, part p = bid>>1 (0..19).
// Thread (rr = tid>>2, u = tid&3), rr<40: gate g = rr/10, q = rr%10,
// grow = g*200 + p*10 + q; col range [u*50, u*50+50) as 25 float2 chunks.
// Block owns h slice [p*10, p*10+10). hbuf: u64[2 slot][2 dir][200].
__global__ __launch_bounds__(192, 2)
void k_scan(const float* __restrict__ Whh,   // [2][2][800][200]
            const float* __restrict__ pre,   // [512][1600]
            float* __restrict__ hs,          // [512][400] (concat fwd|bwd)
            u64* hbuf,                       // zeroed by host each launch
            int layer)
{
  const int bid = blockIdx.x;
  const int dir = bid & 1;
  const int p = bid >> 1;
  const int tid = threadIdx.x;
  const int rr = tid >> 2;           // 0..47
  const int u = tid & 3;
  const bool act = rr < ROWS;
  const int g = rr / HPB;
  const int q = rr - g * HPB;
  const int grow = act ? (g * HDIR + p * HPB + q) : 0;
  const int own0 = p * HPB;

  __shared__ float h_lds[HDIR];
  __shared__ float g_lds[ROWS];      // activated gate values [g*10+q]

  const float* wbase = Whh + ((size_t)(layer * 2 + dir) * G4 + grow) * HDIR + u * 50;
  u64* hb_dir = hbuf + dir * HDIR;   // + slot*400

  for (int i = tid; i < HDIR; i += 192) h_lds[i] = 0.f;
  float c_state = 0.f;               // valid for tid < HPB
  int ofs = 0;                       // t % 25, maintained incrementally
  __syncthreads();

  for (int t = 0; t < TSEQ; ++t) {
    const int inrow = dir ? (TSEQ - 1 - t) : t;

    // ---- phase A: issue the weight stream + pre load EARLY (h-independent).
    // Rotated chunk order (ofs) keeps addresses t-variant: no hoist, no remat.
    float2 wv[25];
    float preval = 0.f;
    if (act) {
      int c = ofs;
#pragma unroll
      for (int i = 0; i < 25; ++i) {
        wv[i] = *(const float2*)(wbase + c * 2);
        c = (c == 24) ? 0 : c + 1;
      }
      if (u == 0) preval = pre[(size_t)inrow * 1600 + dir * G4 + grow];
    }
    __builtin_amdgcn_sched_barrier(0);   // pin: loads stay issued before the spin

    // ---- phase B: gather 190 remote h words (1 per thread); tag carries data.
    // The spin's first waitcnt drains the weight stream -> latencies overlap.
    if (t > 0 && tid < HDIR - HPB) {
      const int j = (tid < own0) ? tid : tid + HPB;
      const u64* src = hb_dir + (size_t)(t & 1) * 400 + j;
      u64 v;
      do {
        v = __hip_atomic_load(src, __ATOMIC_RELAXED, __HIP_MEMORY_SCOPE_AGENT);
      } while ((unsigned)(v >> 32) < (unsigned)t);
      union { unsigned uu; float f; } cv; cv.uu = (unsigned)v;
      h_lds[j] = cv.f;
    }
    __syncthreads();   // B1: h_lds complete (own slice written end of prev iter)

    // ---- phase C: FMA + 4-lane reduce + activation
    if (act) {
      float ax = 0.f, ay = 0.f;
      const float* hb = h_lds + u * 50;
      int c = ofs;
#pragma unroll
      for (int i = 0; i < 25; ++i) {
        const float2 hv = *(const float2*)(hb + c * 2);
        ax += wv[i].x * hv.x; ay += wv[i].y * hv.y;
        c = (c == 24) ? 0 : c + 1;
      }
      float tot = ax + ay;
      tot += __shfl_xor(tot, 1);
      tot += __shfl_xor(tot, 2);
      if (u == 0) {
        const float gv = tot + preval;
        const float xx = (g == 2) ? 2.f * gv : gv;   // tanh = 2*sig(2x)-1
        const float s = 1.f / (1.f + __expf(-xx));
        g_lds[rr] = (g == 2) ? (2.f * s - 1.f) : s;
      }
    }
    __syncthreads();   // B2: g_lds ready

    // ---- phase D: pointwise + publish (tid < 10)
    if (tid < HPB) {
      const float ai = g_lds[tid];
      const float af = g_lds[HPB + tid];
      const float ag = g_lds[2 * HPB + tid];
      const float ao = g_lds[3 * HPB + tid];
      c_state = af * c_state + ai * ag;
      const float th = 2.f / (1.f + __expf(-2.f * c_state)) - 1.f;
      const float hv = ao * th;
      if (t != TSEQ - 1) {           // publish first: critical L2 word leaves early
        union { float f; unsigned uu; } cv; cv.f = hv;
        const u64 pk = ((u64)(unsigned)(t + 1) << 32) | cv.uu;
        __hip_atomic_store(hb_dir + (size_t)((t + 1) & 1) * 400 + own0 + tid,
                           pk, __ATOMIC_RELAXED, __HIP_MEMORY_SCOPE_AGENT);
      }
      h_lds[own0 + tid] = hv;
      hs[(size_t)inrow * INSZ + dir * HDIR + own0 + tid] = hv;
    }
    ofs = (ofs == 24) ? 0 : ofs + 1;
    // no 3rd barrier: next iter's gather touches disjoint h_lds entries, and
    // B1 orders the own-slice write before the next FMA reads it.
  }
}

// ---------------- host ----------------
extern "C" void kernel_launch(void* const* d_in, const int* in_sizes, int n_in,
                              void* d_out, int out_size, void* d_ws, size_t ws_size,
                              hipStream_t stream)
{
  const float* we   = (const float*)d_in[0];
  const float* pe   = (const float*)d_in[1];
  const float* Wih  = (const float*)d_in[2];
  const float* Whh  = (const float*)d_in[3];
  const float* bih  = (const float*)d_in[4];
  const float* bhh  = (const float*)d_in[5];
  const float* W_h1 = (const float*)d_in[6];
  const float* b_h1 = (const float*)d_in[7];
  const float* W_h2 = (const float*)d_in[8];
  const float* b_h2 = (const float*)d_in[9];
  const float* W_d1 = (const float*)d_in[10];
  const float* b_d1 = (const float*)d_in[11];
  const float* W_d2 = (const float*)d_in[12];
  const float* b_d2 = (const float*)d_in[13];
  const float* W_bi = (const float*)d_in[14];
  const float* b_bi = (const float*)d_in[15];
  const int*   wi   = (const int*)d_in[16];
  const int*   pi   = (const int*)d_in[17];
  float* out = (float*)d_out;

  float* ws = (float*)d_ws;
  float* x0   = ws;                     // 512*400
  float* pre  = ws + 204800;            // 512*1600
  float* h1   = ws + 1024000;           // 512*400
  float* h2   = ws + 1228800;           // 512*400
  float* m1h  = ws + 1433600;           // 512*400
  float* m1d  = ws + 1638400;           // 512*400
  float* m2   = ws + 1843200;           // 512*400 (head)
  float* m3   = ws + 2048000;           // 512*400 (dep)
  float* t1   = ws + 2252800;           // 512*400
  float* bsum = ws + 2457600;           // 3200
  u64* hbuf0  = (u64*)(ws + 2461696);   // 800 u64, layer 0
  u64* hbuf1  = hbuf0 + 800;            // layer 1

  hipMemsetAsync(hbuf0, 0, 2 * 800 * sizeof(u64), stream);
  k_embed<<<TSEQ, 128, 0, stream>>>(we, pe, wi, pi, x0);
  k_add<<<(3200 + 255) / 256, 256, 0, stream>>>(bih, bhh, bsum, 3200);

  // layer 0
  k_gemm_bt<<<dim3(25, 8), 256, 0, stream>>>(x0, Wih, bsum, pre, 1600, 400, 1, 0);
  k_scan<<<40, 192, 0, stream>>>(Whh, pre, h1, hbuf0, 0);
  // layer 1
  k_gemm_bt<<<dim3(25, 8), 256, 0, stream>>>(h1, Wih + 1600 * 400, bsum + 1600, pre, 1600, 400, 1, 0);
  k_scan<<<40, 192, 0, stream>>>(Whh, pre, h2, hbuf1, 1);

  // head/dep stage 1 (dual), stage 2 (dual)
  k_gemm_bt_dual<<<dim3(7, 8, 2), 256, 0, stream>>>(h2, W_h1, b_h1, m1h,
                                                    h2, W_d1, b_d1, m1d, 400, 400, 1, 1);
  k_gemm_bt_dual<<<dim3(7, 8, 2), 256, 0, stream>>>(m1h, W_h2, b_h2, m2,
                                                    m1d, W_d2, b_d2, m3, 400, 400, 1, 1);

  // bilinear: t1[j][d] = sum_e dep[j][e] W_bi[d][e]; out[i][j] = head_i . t1_j + b
  k_gemm_bt<<<dim3(7, 8), 256, 0, stream>>>(m3, W_bi, nullptr, t1, 400, 400, 0, 0);
  k_gemm_bt<<<dim3(8, 8), 256, 0, stream>>>(m2, t1, b_bi, out, 512, 400, 2, 0);
}

// Round 10
// 1811.488 us; speedup vs baseline: 1.3136x; 1.3136x over previous
//
#include <hip/hip_runtime.h>
#include <hip/hip_bf16.h>
#include <cstdint>
#include <cstddef>

// BiLSTM tagger, f32 end-to-end.
// embed -> [GEMM pre -> 16-block LDS-resident LSTM scan] x2 -> MLP GEMMs -> bilinear.
// Scan (r10): weights live in LDS, staged ONCE (coalesced), zero per-step VMEM for
// weights. r3-r9 showed: VGPR-resident weights impossible (allocator remat/spill),
// L2-streamed weights transaction-bound (uncoalesced per-lane rows). 16 working
// blocks = 2 dirs x 8 parts; each block: 100 gate rows x 200 cols = 81.6 KB LDS
// (dynamic, >64KB via hipFuncSetAttribute). Thread = 8-lane group (hq: 4 gates x
// 2 col-halves) -> gate exchange via in-wave __shfl, h_lds double-buffered by
// parity -> ONE barrier/step. Cross-block h via packed (tag<<32|val) u64 in L2;
// 64-block launch with bid%8 in {0,1} working pins all 8 partners of a dir to one
// XCD (if XCD = bid%8; perf-only assumption).

#define TSEQ 512
#define HDIR 200
#define INSZ 400
#define G4   800
#define HPB  25      // h-indices per block
#define SW   204     // LDS row stride (floats); 204%32=12 -> 4-way worst case

typedef unsigned long long u64;

// ---------------- embedding ----------------
__global__ void k_embed(const float* __restrict__ we, const float* __restrict__ pe,
                        const int* __restrict__ wi, const int* __restrict__ pi,
                        float* __restrict__ x) {
  int t = blockIdx.x;
  int w = wi[t], p = pi[t];
  const float* wrow = we + (size_t)w * 300;
  const float* prow = pe + (size_t)p * 100;
  for (int j = threadIdx.x; j < INSZ; j += blockDim.x)
    x[(size_t)t * INSZ + j] = (j < 300) ? wrow[j] : prow[j - 300];
}

__global__ void k_add(const float* __restrict__ a, const float* __restrict__ b,
                      float* __restrict__ o, int n) {
  int i = blockIdx.x * blockDim.x + threadIdx.x;
  if (i < n) o[i] = a[i] + b[i];
}

// ---------------- GEMM: C[n][m] = act(A[n][k] * B[m][k]^T + bias) ----------------
__device__ __forceinline__ void gemm_bt_body(
    const float* __restrict__ A, const float* __restrict__ B,
    const float* __restrict__ bias, float* __restrict__ C,
    int m, int k, int bias_mode, int do_relu, int bx, int by)
{
  __shared__ float As[16][68];
  __shared__ float Bs[16][68];
  const int tid = threadIdx.x;
  const int tx = tid & 15, ty = tid >> 4;
  const int row0 = by << 6, col0 = bx << 6;
  const int lr = tid >> 2;
  const int kq = (tid & 3) << 2;
  float acc[4][4] = {};

  for (int ks = 0; ks < k; ks += 16) {
    float4 a4 = *(const float4*)(A + (size_t)(row0 + lr) * k + ks + kq);
    float4 b4 = make_float4(0.f, 0.f, 0.f, 0.f);
    if (col0 + lr < m)
      b4 = *(const float4*)(B + (size_t)(col0 + lr) * k + ks + kq);
    As[kq + 0][lr] = a4.x; As[kq + 1][lr] = a4.y; As[kq + 2][lr] = a4.z; As[kq + 3][lr] = a4.w;
    Bs[kq + 0][lr] = b4.x; Bs[kq + 1][lr] = b4.y; Bs[kq + 2][lr] = b4.z; Bs[kq + 3][lr] = b4.w;
    __syncthreads();
#pragma unroll
    for (int kk = 0; kk < 16; ++kk) {
      const float4 av = *(const float4*)&As[kk][ty << 2];
      const float4 bv = *(const float4*)&Bs[kk][tx << 2];
      const float a_[4] = {av.x, av.y, av.z, av.w};
      const float b_[4] = {bv.x, bv.y, bv.z, bv.w};
#pragma unroll
      for (int i = 0; i < 4; ++i)
#pragma unroll
        for (int j = 0; j < 4; ++j)
          acc[i][j] += a_[i] * b_[j];
    }
    __syncthreads();
  }

#pragma unroll
  for (int i = 0; i < 4; ++i) {
    const int r = row0 + (ty << 2) + i;
#pragma unroll
    for (int j = 0; j < 4; ++j) {
      const int c = col0 + (tx << 2) + j;
      if (c < m) {
        float v = acc[i][j];
        if (bias_mode == 1) v += bias[c];
        else if (bias_mode == 2) v += bias[0];
        if (do_relu) v = fmaxf(v, 0.f);
        C[(size_t)r * m + c] = v;
      }
    }
  }
}

__global__ __launch_bounds__(256) void k_gemm_bt(
    const float* __restrict__ A, const float* __restrict__ B,
    const float* __restrict__ bias, float* __restrict__ C,
    int m, int k, int bias_mode, int do_relu)
{
  gemm_bt_body(A, B, bias, C, m, k, bias_mode, do_relu, blockIdx.x, blockIdx.y);
}

__global__ __launch_bounds__(256) void k_gemm_bt_dual(
    const float* __restrict__ A0, const float* __restrict__ B0,
    const float* __restrict__ bias0, float* __restrict__ C0,
    const float* __restrict__ A1, const float* __restrict__ B1,
    const float* __restrict__ bias1, float* __restrict__ C1,
    int m, int k, int bias_mode, int do_relu)
{
  const float* A = blockIdx.z ? A1 : A0;
  const float* B = blockIdx.z ? B1 : B0;
  const float* bias = blockIdx.z ? bias1 : bias0;
  float* C = blockIdx.z ? C1 : C0;
  gemm_bt_body(A, B, bias, C, m, k, bias_mode, do_relu, blockIdx.x, blockIdx.y);
}

// ---------------- LSTM scan ----------------
// Working blocks: bid%8 in {0,1}: dir = bid&7, part p = bid>>3 (0..7).
// Thread tid<200: hq = tid>>3 (0..24), g = (tid>>1)&3, u = tid&1.
// LDS: w_lds[100][SW] (row = g*25+hq, cols u*100..+99), h double-buffered [2][200].
// hbuf: u64[2 slot][2 dir][200], word = (tag<<32)|bits(h).
__global__ __launch_bounds__(256)
void k_scan(const float* __restrict__ Whh,   // [2][2][800][200]
            const float* __restrict__ pre,   // [512][1600]
            float* __restrict__ hs,          // [512][400] (concat fwd|bwd)
            u64* hbuf,                       // zeroed by host each launch
            int layer)
{
  const int bid = blockIdx.x;
  if ((bid & 7) > 1) return;               // 16 working blocks; XCD co-location
  const int dir = bid & 7;
  const int p = bid >> 3;
  const int tid = threadIdx.x;
  const int hq = tid >> 3;
  const int g = (tid >> 1) & 3;
  const int u = tid & 1;
  const bool act = tid < 200;
  const int own0 = p * HPB;
  const int grow = g * HDIR + own0 + hq;   // valid for act threads

  extern __shared__ float smem[];
  float* w_lds = smem;                     // [100][SW]
  float* h_lds = smem + 100 * SW;          // [2][200]

  const float* WhhL = Whh + (size_t)(layer * 2 + dir) * G4 * HDIR;
  u64* hb_dir = hbuf + dir * HDIR;         // + slot*400

  // ---- one-time staging: 100 rows x 200 cols, coalesced float4 ----
  for (int idx = tid; idx < 100 * 50; idx += 256) {
    const int lr = idx / 50;               // local row 0..99
    const int c4 = idx - lr * 50;          // float4 col chunk 0..49
    const int gg = lr / 25, qq = lr - gg * 25;
    const float4 v = *(const float4*)(WhhL + ((size_t)(gg * HDIR + own0 + qq)) * HDIR + c4 * 4);
    *(float4*)(w_lds + lr * SW + c4 * 4) = v;
  }
  for (int i = tid; i < 400; i += 256) h_lds[i] = 0.f;   // both parity buffers
  float c_state = 0.f;                     // valid at owner lanes (tid%8==0, act)
  __syncthreads();

  for (int t = 0; t < TSEQ; ++t) {
    const int inrow = dir ? (TSEQ - 1 - t) : t;

    float preval = 0.f;
    if (act && u == 0)                      // issue early; h-independent
      preval = pre[(size_t)inrow * 1600 + dir * G4 + grow];

    // gather 175 remote words into h_lds[t&1] (tag carries the data)
    if (t > 0 && tid < HDIR - HPB) {
      const int j = (tid < own0) ? tid : tid + HPB;
      const u64* src = hb_dir + (size_t)(t & 1) * 400 + j;
      u64 v;
      do {
        v = __hip_atomic_load(src, __ATOMIC_RELAXED, __HIP_MEMORY_SCOPE_AGENT);
      } while ((unsigned)(v >> 32) < (unsigned)t);
      union { unsigned uu; float f; } cv; cv.uu = (unsigned)v;
      h_lds[(t & 1) * HDIR + j] = cv.f;
    }
    __syncthreads();                        // the ONLY barrier per step

    float av = 0.f;
    if (act) {
      const float* hb = h_lds + (t & 1) * HDIR + u * 100;
      const float* wb = w_lds + (g * 25 + hq) * SW + u * 100;
      float ax = 0.f, ay = 0.f, az = 0.f, aw = 0.f;
#pragma unroll
      for (int i = 0; i < 25; ++i) {
        const float4 wv = *(const float4*)(wb + i * 4);
        const float4 hv = *(const float4*)(hb + i * 4);
        ax += wv.x * hv.x; ay += wv.y * hv.y;
        az += wv.z * hv.z; aw += wv.w * hv.w;
      }
      float tot = ax + ay + az + aw;
      tot += __shfl_xor(tot, 1);            // combine col halves (u pair)
      const float gv = tot + preval;        // garbage at u==1 (unused)
      const float xx = (g == 2) ? 2.f * gv : gv;   // tanh = 2*sig(2x)-1
      const float s = 1.f / (1.f + __expf(-xx));
      av = (g == 2) ? (2.f * s - 1.f) : s;
    }
    // gate exchange: all lanes execute the shfls (sources are active lanes)
    const int lb = (tid & 63) & ~7;         // 8-lane group base within wave
    const float af = __shfl(av, lb + 2);
    const float ag = __shfl(av, lb + 4);
    const float ao = __shfl(av, lb + 6);

    if (act && (tid & 7) == 0) {            // owner lane: g==0 (ai=av), u==0
      c_state = af * c_state + av * ag;
      const float th = 2.f / (1.f + __expf(-2.f * c_state)) - 1.f;
      const float hv = ao * th;
      if (t != TSEQ - 1) {                  // publish first
        union { float f; unsigned uu; } cv; cv.f = hv;
        const u64 pk = ((u64)(unsigned)(t + 1) << 32) | cv.uu;
        __hip_atomic_store(hb_dir + (size_t)((t + 1) & 1) * 400 + own0 + hq,
                           pk, __ATOMIC_RELAXED, __HIP_MEMORY_SCOPE_AGENT);
      }
      h_lds[((t + 1) & 1) * HDIR + own0 + hq] = hv;   // next parity buffer
      hs[(size_t)inrow * INSZ + dir * HDIR + own0 + hq] = hv;
    }
    // no 2nd barrier: gather(t+1) writes parity (t+1)&1, FMA(t) read (t&1).
  }
}

// ---------------- host ----------------
extern "C" void kernel_launch(void* const* d_in, const int* in_sizes, int n_in,
                              void* d_out, int out_size, void* d_ws, size_t ws_size,
                              hipStream_t stream)
{
  const float* we   = (const float*)d_in[0];
  const float* pe   = (const float*)d_in[1];
  const float* Wih  = (const float*)d_in[2];
  const float* Whh  = (const float*)d_in[3];
  const float* bih  = (const float*)d_in[4];
  const float* bhh  = (const float*)d_in[5];
  const float* W_h1 = (const float*)d_in[6];
  const float* b_h1 = (const float*)d_in[7];
  const float* W_h2 = (const float*)d_in[8];
  const float* b_h2 = (const float*)d_in[9];
  const float* W_d1 = (const float*)d_in[10];
  const float* b_d1 = (const float*)d_in[11];
  const float* W_d2 = (const float*)d_in[12];
  const float* b_d2 = (const float*)d_in[13];
  const float* W_bi = (const float*)d_in[14];
  const float* b_bi = (const float*)d_in[15];
  const int*   wi   = (const int*)d_in[16];
  const int*   pi   = (const int*)d_in[17];
  float* out = (float*)d_out;

  float* ws = (float*)d_ws;
  float* x0   = ws;                     // 512*400
  float* pre  = ws + 204800;            // 512*1600
  float* h1   = ws + 1024000;           // 512*400
  float* h2   = ws + 1228800;           // 512*400
  float* m1h  = ws + 1433600;           // 512*400
  float* m1d  = ws + 1638400;           // 512*400
  float* m2   = ws + 1843200;           // 512*400 (head)
  float* m3   = ws + 2048000;           // 512*400 (dep)
  float* t1   = ws + 2252800;           // 512*400
  float* bsum = ws + 2457600;           // 3200
  u64* hbuf0  = (u64*)(ws + 2461696);   // 800 u64, layer 0
  u64* hbuf1  = hbuf0 + 800;            // layer 1

  const int SMEM = (100 * SW + 400) * 4;  // 83,200 B dynamic LDS
  static int attr_done = 0;
  hipFuncSetAttribute((const void*)k_scan,
                      hipFuncAttributeMaxDynamicSharedMemorySize, SMEM);
  (void)attr_done;

  hipMemsetAsync(hbuf0, 0, 2 * 800 * sizeof(u64), stream);
  k_embed<<<TSEQ, 128, 0, stream>>>(we, pe, wi, pi, x0);
  k_add<<<(3200 + 255) / 256, 256, 0, stream>>>(bih, bhh, bsum, 3200);

  // layer 0
  k_gemm_bt<<<dim3(25, 8), 256, 0, stream>>>(x0, Wih, bsum, pre, 1600, 400, 1, 0);
  k_scan<<<64, 256, SMEM, stream>>>(Whh, pre, h1, hbuf0, 0);
  // layer 1
  k_gemm_bt<<<dim3(25, 8), 256, 0, stream>>>(h1, Wih + 1600 * 400, bsum + 1600, pre, 1600, 400, 1, 0);
  k_scan<<<64, 256, SMEM, stream>>>(Whh, pre, h2, hbuf1, 1);

  // head/dep stage 1 (dual), stage 2 (dual)
  k_gemm_bt_dual<<<dim3(7, 8, 2), 256, 0, stream>>>(h2, W_h1, b_h1, m1h,
                                                    h2, W_d1, b_d1, m1d, 400, 400, 1, 1);
  k_gemm_bt_dual<<<dim3(7, 8, 2), 256, 0, stream>>>(m1h, W_h2, b_h2, m2,
                                                    m1d, W_d2, b_d2, m3, 400, 400, 1, 1);

  // bilinear: t1[j][d] = sum_e dep[j][e] W_bi[d][e]; out[i][j] = head_i . t1_j + b
  k_gemm_bt<<<dim3(7, 8), 256, 0, stream>>>(m3, W_bi, nullptr, t1, 400, 400, 0, 0);
  k_gemm_bt<<<dim3(8, 8), 256, 0, stream>>>(m2, t1, b_bi, out, 512, 400, 2, 0);
}